// Round 1
// baseline (201.753 us; speedup 1.0000x reference)
//
#include <hip/hip_runtime.h>
#include <hip/hip_bf16.h>
#include <math.h>

// Shapes: B=8, T1=512, T2=128, LA=128, E=64, G=3E=192, DL=256
#define Bn 8
#define T1n 512
#define T2n 128
#define En 64
#define Gn 192
#define DLn 256

// ---------------------------------------------------------------------------
// K1: xg[d][b][t][j] = b_d[0][j] + sum_e emb_table[char_seq[b][t]][e] * K_d[e][j]
// grid: B*T2 = 1024 blocks, 384 threads (2 dirs x 192 gates)
// ---------------------------------------------------------------------------
__global__ __launch_bounds__(384) void k_xg(const int* __restrict__ char_seq,
                                            const float* __restrict__ emb_table,
                                            const float* __restrict__ Kf,
                                            const float* __restrict__ bf,
                                            const float* __restrict__ Kb,
                                            const float* __restrict__ bb,
                                            float* __restrict__ xg) {
    int bt = blockIdx.x;              // 0..1023
    int b = bt >> 7, t = bt & 127;
    int tid = threadIdx.x;            // 0..383
    __shared__ __align__(16) float emb[En];
    if (tid < En) {
        int cs = char_seq[b * T2n + t];
        emb[tid] = emb_table[cs * En + tid];
    }
    __syncthreads();
    int d = tid / Gn;                 // wave-uniform (192 = 3 waves)
    int j = tid - d * Gn;
    const float* K = d ? Kb : Kf;
    const float* bias = d ? bb : bf;  // row 0
    float acc = bias[j];
    #pragma unroll
    for (int e = 0; e < En; ++e) acc = fmaf(emb[e], K[e * Gn + j], acc);
    xg[((d * Bn + b) * T2n + t) * Gn + j] = acc;
}

// ---------------------------------------------------------------------------
// K2: sL[b][t] = dot(lstm[b][t][:], w_char[0:256])
// grid: 1024 blocks x 256 threads; one wave per (b,t)
// ---------------------------------------------------------------------------
__global__ __launch_bounds__(256) void k_sL(const float* __restrict__ lstm,
                                            const float* __restrict__ w_char,
                                            float* __restrict__ sL) {
    int wave = threadIdx.x >> 6;
    int lane = threadIdx.x & 63;
    int bt = blockIdx.x * 4 + wave;   // 0..4095
    const float4* row = (const float4*)(lstm + (size_t)bt * DLn);
    const float4* wl  = (const float4*)(w_char);
    float4 r = row[lane];
    float4 w = wl[lane];
    float s = r.x * w.x + r.y * w.y + r.z * w.z + r.w * w.w;
    #pragma unroll
    for (int off = 32; off; off >>= 1) s += __shfl_down(s, off);
    if (lane == 0) sL[bt] = s;
}

// ---------------------------------------------------------------------------
// K3: the sequential GRU scan. grid: 16 blocks = (b, dir), 192 threads.
// Thread j owns gate column j (R[:,j] in registers). h lives in LDS.
// ctx[b][s][d*64+u] = y
// ---------------------------------------------------------------------------
__global__ __launch_bounds__(192) void k_scan(const float* __restrict__ xg,
                                              const float* __restrict__ Rf,
                                              const float* __restrict__ bf,
                                              const float* __restrict__ Rb,
                                              const float* __restrict__ bb,
                                              const int* __restrict__ char_seq,
                                              float* __restrict__ ctx) {
    int blk = blockIdx.x;             // 0..15
    int b = blk & 7, d = blk >> 3;
    int j = threadIdx.x;              // 0..191
    const float* R = d ? Rb : Rf;
    const float* bias = (d ? bb : bf) + Gn;   // b[1]
    float Rcol[En];
    #pragma unroll
    for (int k = 0; k < En; ++k) Rcol[k] = R[k * Gn + j];
    float b1j = bias[j];

    __shared__ __align__(16) float h[En];
    __shared__ float rg[Gn];
    __shared__ float xrow[Gn];
    __shared__ int mloc[T2n];
    if (j < En) h[j] = 0.f;
    if (j < T2n) mloc[j] = char_seq[b * T2n + j];
    float hreg = 0.f, y = 0.f;
    const float* xgbase = xg + (size_t)(d * Bn + b) * T2n * Gn;
    float* ctxbase = ctx + (size_t)b * T2n * 128 + d * En;
    __syncthreads();

    for (int step = 0; step < T2n; ++step) {
        int idx = d ? (T2n - 1 - step) : step;
        float xt = xgbase[idx * Gn + j];   // issue early; L2-resident
        float acc = b1j;
        const float4* h4 = (const float4*)h;
        #pragma unroll
        for (int k4 = 0; k4 < En / 4; ++k4) {
            float4 hv = h4[k4];
            acc = fmaf(hv.x, Rcol[4 * k4 + 0], acc);
            acc = fmaf(hv.y, Rcol[4 * k4 + 1], acc);
            acc = fmaf(hv.z, Rcol[4 * k4 + 2], acc);
            acc = fmaf(hv.w, Rcol[4 * k4 + 3], acc);
        }
        rg[j] = acc;
        xrow[j] = xt;
        __syncthreads();
        if (j < En) {
            float xz = xrow[j], xr = xrow[En + j], xh = xrow[2 * En + j];
            float rz = rg[j],   rr = rg[En + j],   rh = rg[2 * En + j];
            float z = 1.f / (1.f + __expf(-(xz + rz)));
            float r = 1.f / (1.f + __expf(-(xr + rr)));
            float hh = tanhf(xh + r * rh);
            float hn = z * hreg + (1.f - z) * hh;
            if (mloc[idx] != 0) { hreg = hn; y = hn; }
            h[j] = hreg;
            ctxbase[idx * 128 + j] = y;
        }
        __syncthreads();
    }
}

// ---------------------------------------------------------------------------
// K4: per (b,s): P0/P1 = ctx_row @ W1[tap], then
//   A  = P0@W20, Cm = P1@W21, Bm = P1@W20 + P0@W21, and sC = ctx_row . w_c
// grid: 1024 blocks x 128 threads
// ---------------------------------------------------------------------------
__global__ __launch_bounds__(128) void k_ctxw(const float* __restrict__ ctx,
                                              const float* __restrict__ conv1_w,
                                              const float* __restrict__ conv2_w,
                                              const float* __restrict__ w_char,
                                              float* __restrict__ Am,
                                              float* __restrict__ Bm,
                                              float* __restrict__ Cm,
                                              float* __restrict__ sC) {
    int bs = blockIdx.x;              // b*128+s
    int tid = threadIdx.x;            // 0..127
    __shared__ float crow[128];
    __shared__ float p0[En], p1[En];
    crow[tid] = ctx[(size_t)bs * 128 + tid];
    __syncthreads();
    if (tid < 64) {                   // sC reduction on wave 0 (redundant-free)
        float s = crow[tid] * w_char[DLn + tid] + crow[64 + tid] * w_char[DLn + 64 + tid];
        #pragma unroll
        for (int off = 32; off; off >>= 1) s += __shfl_down(s, off);
        if (tid == 0) sC[bs] = s;
    }
    int tap = tid >> 6, o = tid & 63;
    const float* W = conv1_w + tap * 128 * En;
    float acc = 0.f;
    #pragma unroll
    for (int c = 0; c < 128; ++c) acc = fmaf(crow[c], W[c * En + o], acc);
    if (tap == 0) p0[o] = acc; else p1[o] = acc;
    __syncthreads();
    const float* W20 = conv2_w;            // [64][64]
    const float* W21 = conv2_w + En * En;
    if (tid < 64) {
        float a = 0.f, cm = 0.f;
        #pragma unroll
        for (int c = 0; c < En; ++c) {
            a  = fmaf(p0[c], W20[c * En + tid], a);
            cm = fmaf(p1[c], W21[c * En + tid], cm);
        }
        Am[(size_t)bs * En + tid] = a;
        Cm[(size_t)bs * En + tid] = cm;
    } else {
        int o2 = tid - 64;
        float bacc = 0.f;
        #pragma unroll
        for (int c = 0; c < En; ++c) {
            bacc = fmaf(p1[c], W20[c * En + o2], bacc);
            bacc = fmaf(p0[c], W21[c * En + o2], bacc);
        }
        Bm[(size_t)bs * En + o2] = bacc;
    }
}

// ---------------------------------------------------------------------------
// K5: per (b, 8-t tile): score rows -> char_weights; then
//   fe[b,t,o] = max_s ( sc[s]*A[s,o] + sc[s+1]*Bm[s+1,o] + sc[s+2]*Cm[s+2,o] + bb2[o] )
// grid: 512 blocks x 128 threads
// ---------------------------------------------------------------------------
__global__ __launch_bounds__(128) void k_final(const float* __restrict__ sL,
                                               const float* __restrict__ sC,
                                               const float* __restrict__ w_char,
                                               const float* __restrict__ b_char,
                                               const float* __restrict__ conv1_b,
                                               const float* __restrict__ conv2_w,
                                               const float* __restrict__ conv2_b,
                                               const float* __restrict__ Am,
                                               const float* __restrict__ Bm,
                                               const float* __restrict__ Cm,
                                               float* __restrict__ fe,
                                               float* __restrict__ cw) {
    int blk = blockIdx.x;             // b(3b) x ttile(6b)
    int b = blk >> 6, ttile = blk & 63;
    int t0 = ttile * 8;
    int tid = threadIdx.x;            // 0..127
    float w_t = w_char[DLn + 128], w_i = w_char[DLn + 129], bc = b_char[0];
    __shared__ float sc8[8][T2n];
    {
        int s = tid;
        float sCs = sC[b * T2n + s] + w_i * (float)s + bc;
        #pragma unroll
        for (int tt = 0; tt < 8; ++tt) {
            int t = t0 + tt;
            float v = sL[b * T1n + t] + sCs + w_t * (float)t;
            sc8[tt][s] = v;
            cw[((size_t)(b * T1n + t)) * T2n + s] = v;
        }
    }
    int o = tid & 63, p = tid >> 6;
    // bb2[o] = conv2_b[o] + sum_c conv1_b[c]*(W20[c,o]+W21[c,o])
    float bb2 = conv2_b[o];
    #pragma unroll
    for (int c = 0; c < En; ++c)
        bb2 += conv1_b[c] * (conv2_w[c * En + o] + conv2_w[En * En + c * En + o]);
    __syncthreads();

    float acc[8];
    #pragma unroll
    for (int tt = 0; tt < 8; ++tt) acc[tt] = -__builtin_inff();
    const float* Ab = Am + (size_t)(b * T2n) * En + o;
    const float* Bb = Bm + (size_t)(b * T2n) * En + o;
    const float* Cb = Cm + (size_t)(b * T2n) * En + o;
    for (int s = p; s < T2n - 2; s += 2) {
        float a  = Ab[s * En];
        float bm = Bb[(s + 1) * En];
        float cm = Cb[(s + 2) * En];
        #pragma unroll
        for (int tt = 0; tt < 8; ++tt) {
            float v = fmaf(sc8[tt][s], a,
                      fmaf(sc8[tt][s + 1], bm,
                      fmaf(sc8[tt][s + 2], cm, bb2)));
            acc[tt] = fmaxf(acc[tt], v);
        }
    }
    __shared__ float red[64][9];      // +1 pad vs bank conflict
    if (p == 1) {
        #pragma unroll
        for (int tt = 0; tt < 8; ++tt) red[o][tt] = acc[tt];
    }
    __syncthreads();
    if (p == 0) {
        #pragma unroll
        for (int tt = 0; tt < 8; ++tt) {
            float v = fmaxf(acc[tt], red[o][tt]);
            fe[((size_t)(b * T1n + t0 + tt)) * En + o] = v;
        }
    }
}

// ---------------------------------------------------------------------------
extern "C" void kernel_launch(void* const* d_in, const int* in_sizes, int n_in,
                              void* d_out, int out_size, void* d_ws, size_t ws_size,
                              hipStream_t stream) {
    const float* lstm      = (const float*)d_in[0];
    const int*   char_seq  = (const int*)d_in[1];
    const float* emb_table = (const float*)d_in[2];
    const float* Kf        = (const float*)d_in[3];
    const float* Rf        = (const float*)d_in[4];
    const float* bf        = (const float*)d_in[5];
    const float* Kb        = (const float*)d_in[6];
    const float* Rb        = (const float*)d_in[7];
    const float* bb        = (const float*)d_in[8];
    const float* w_char    = (const float*)d_in[9];
    const float* b_char    = (const float*)d_in[10];
    const float* conv1_w   = (const float*)d_in[11];
    const float* conv1_b   = (const float*)d_in[12];
    const float* conv2_w   = (const float*)d_in[13];
    const float* conv2_b   = (const float*)d_in[14];

    float* out = (float*)d_out;
    float* fe = out;                             // 8*512*64 = 262144
    float* cw = out + Bn * T1n * En;             // 8*512*128 = 524288

    float* ws  = (float*)d_ws;
    float* xg  = ws;                             // 2*8*128*192 = 393216
    float* ctx = xg + 2 * Bn * T2n * Gn;         // 8*128*128  = 131072
    float* sC  = ctx + Bn * T2n * 128;           // 1024
    float* sL  = sC + Bn * T2n;                  // 4096
    float* Am  = sL + Bn * T1n;                  // 65536
    float* Bm  = Am + Bn * T2n * En;             // 65536
    float* Cm  = Bm + Bn * T2n * En;             // 65536

    k_xg  <<<Bn * T2n, 384, 0, stream>>>(char_seq, emb_table, Kf, bf, Kb, bb, xg);
    k_sL  <<<(Bn * T1n) / 4, 256, 0, stream>>>(lstm, w_char, sL);
    k_scan<<<16, 192, 0, stream>>>(xg, Rf, bf, Rb, bb, char_seq, ctx);
    k_ctxw<<<Bn * T2n, 128, 0, stream>>>(ctx, conv1_w, conv2_w, w_char, Am, Bm, Cm, sC);
    k_final<<<(Bn * T1n) / 8, 128, 0, stream>>>(sL, sC, w_char, b_char, conv1_b,
                                                conv2_w, conv2_b, Am, Bm, Cm, fe, cw);
}